// Round 18
// baseline (187.044 us; speedup 1.0000x reference)
//
#include <hip/hip_runtime.h>
#include <hip/hip_bf16.h>

typedef short short8 __attribute__((ext_vector_type(8)));
typedef float floatx4 __attribute__((ext_vector_type(4)));

#define NGROUP 512
#define RREG 256
#define D 512
#define ROWS 131072
#define FBAR_ELEMS (NGROUP * D)   // 262144

__device__ __forceinline__ unsigned short f2bf(float f) {
    unsigned int u = __float_as_uint(f);
    unsigned int r = (u + 0x7fffu + ((u >> 16) & 1u)) >> 16;
    return (unsigned short)r;
}
__device__ __forceinline__ float fast_tanh(float x) {
    // 1 - 2/(e^{2x}+1); no clamp needed: exp->inf gives 1, exp->0 gives -1.
    float e = __builtin_amdgcn_exp2f(x * 2.8853900817779268f);
    return 1.0f - 2.0f * __builtin_amdgcn_rcpf(e + 1.0f);
}

// ---- kernel 1: W1 fp32 -> bf16, K-CHUNKED PRE-SWIZZLED layout (R16 verbatim) ----
// W1c = 16 chunks of 32 KiB. Chunk kc holds k in [kc*32,kc*32+32) for all 512
// cols: element (col, kc*32+kl) at chunk byte col*64 + ((kl*2) ^ (((col>>1)&3)<<4)).
__global__ __launch_bounds__(256) void conv_w1(const float* __restrict__ W1,
                                               unsigned short* __restrict__ W1c) {
    int tid = blockIdx.x * 256 + threadIdx.x;   // 0..65535
    int P = tid * 8;                            // byte offset in 512 KiB image
    int kc = P >> 15;
    int L = P & 32767;
    int col = L >> 6;
    int q = L & 63;
    int kl = (q ^ (((col >> 1) & 3) << 4)) >> 1;   // multiple of 4
    const float* src = W1 + col * 512 + kc * 32 + kl;
    float4 v = *reinterpret_cast<const float4*>(src);
    ushort4 o;
    o.x = f2bf(v.x); o.y = f2bf(v.y); o.z = f2bf(v.z); o.w = f2bf(v.w);
    *reinterpret_cast<ushort4*>((char*)W1c + P) = o;
}

// ---- kernel 2: score GEMM — barrier-free K-loop ----
// 2048 blocks x 1024 threads (16 waves). Block = 64 rows x full N=512.
// A: staged ONCE into 64 KB LDS (swizzle (row&15)<<6: A-frag reads hit 64
// distinct 16B slots -> uniform 2-way, free). No per-step pack/barrier.
// B: wave-private 2 KB slices (cols w*32..+32) of 32-k chunks, triple-buffered
// (3 x 32 KB), distance-2 prefetch, counted s_waitcnt vmcnt(4) - NEVER a
// barrier in the 16-step loop (A read-only, B wave-private: no cross-wave
// hazard). R16/R17 lesson: per-step __syncthreads (wave convoy + vmcnt(0)
// drain) was the 2.6x-over-pipe-floor multiplier; both barrier-coupled
// structures plateaued at ~160us across occupancy 4 vs 8 waves/SIMD.
// LDS = 65536 + 3*32768 = 163840 B exactly (R10 precedent: fits).
// VGPR: launch_bounds(1024,4) -> cap 64 (R3-verified); acc[4][2]=32 AGPR.
__global__ __launch_bounds__(1024, 4) void score_gemm(
    const float* __restrict__ x, const unsigned short* __restrict__ W1c,
    const float* __restrict__ b1, const float* __restrict__ W2v,
    float* __restrict__ inv_norm, float* __restrict__ scores) {

    __shared__ char A_lds[65536];      // 64 rows x 1 KiB, swizzled
    __shared__ char B_lds[3][32768];   // [buf][16 waves x 2 KB slices]

    const int t = threadIdx.x;
    const int lane = t & 63;
    const int w = t >> 6;          // wave 0..15 -> cols w*32..w*32+32
    const int cl = lane & 15;
    const int hi = lane >> 4;
    const size_t row0 = (size_t)blockIdx.x * 64;

    // wave-private B stage: 32-col slice of chunk kc (2 KB, 2 DMA instrs)
    auto stageB = [&](int buf, int kc) {
        const char* gb = (const char*)W1c + kc * 32768 + w * 2048 + lane * 16;
        char* lb = &B_lds[buf][w * 2048];
        #pragma unroll
        for (int i = 0; i < 2; ++i) {
            __builtin_amdgcn_global_load_lds(
                (const __attribute__((address_space(1))) void*)(gb + i * 1024),
                (__attribute__((address_space(3))) void*)(lb + i * 1024),
                16, 0, 0);
        }
    };

    stageB(0, 0);   // chunks 0,1 in flight during A staging
    stageB(1, 1);

    // ---- stage A once: thread covers row w*4+hi, k-segment (lane&15)*32 ----
    {
        const int srow = w * 4 + hi;
        const int sks = lane & 15;
        const float* xs = x + (row0 + srow) * (size_t)D + sks * 32;
        float4 xv[8];
        #pragma unroll
        for (int j = 0; j < 8; ++j)
            xv[j] = *reinterpret_cast<const float4*>(xs + j * 4);
        float ss = 0.f;
        #pragma unroll
        for (int j = 0; j < 8; ++j)
            ss += xv[j].x*xv[j].x + xv[j].y*xv[j].y + xv[j].z*xv[j].z + xv[j].w*xv[j].w;
        // lanes hi*16+0..15 share row srow
        ss += __shfl_xor(ss, 1, 16);
        ss += __shfl_xor(ss, 2, 16);
        ss += __shfl_xor(ss, 4, 16);
        ss += __shfl_xor(ss, 8, 16);
        if (sks == 0) inv_norm[row0 + srow] = 1.0f / fmaxf(sqrtf(ss), 1e-12f);
        const int akey = (srow & 15) << 6;
        #pragma unroll
        for (int q = 0; q < 4; ++q) {
            float4 p = xv[2 * q], r = xv[2 * q + 1];
            short8 pk;
            pk[0] = (short)f2bf(p.x); pk[1] = (short)f2bf(p.y);
            pk[2] = (short)f2bf(p.z); pk[3] = (short)f2bf(p.w);
            pk[4] = (short)f2bf(r.x); pk[5] = (short)f2bf(r.y);
            pk[6] = (short)f2bf(r.z); pk[7] = (short)f2bf(r.w);
            *reinterpret_cast<short8*>(
                A_lds + srow * 1024 + ((sks * 64 + q * 16) ^ akey)) = pk;
        }
    }
    __syncthreads();   // A visible to all; chunks 0,1 landed (one-time drain)

    // ---- K loop: 16 steps of 32 k; NO barriers, counted vmcnt ----
    floatx4 acc[4][2];
    #pragma unroll
    for (int tt = 0; tt < 4; ++tt) {
        acc[tt][0] = floatx4{0, 0, 0, 0};
        acc[tt][1] = floatx4{0, 0, 0, 0};
    }

    const int fofsB = (hi * 16) ^ (((cl >> 1) & 3) << 4);   // B frag swizzle
    const int aoff = cl << 6;                               // A frag swizzle key

    #pragma unroll
    for (int s = 0; s < 16; ++s) {
        if (s + 2 < 16) stageB((s + 2) % 3, s + 2);   // distance-2 prefetch
        // wait for own chunk s (outstanding: s+1, s+2 = 4 ops stay in flight)
        if (s < 14)       asm volatile("s_waitcnt vmcnt(4)" ::: "memory");
        else if (s == 14) asm volatile("s_waitcnt vmcnt(2)" ::: "memory");
        else              asm volatile("s_waitcnt vmcnt(0)" ::: "memory");

        const char* Bb = &B_lds[s % 3][w * 2048];
        short8 bfr0 = *reinterpret_cast<const short8*>(Bb + cl * 64 + fofsB);
        short8 bfr1 = *reinterpret_cast<const short8*>(Bb + (16 + cl) * 64 + fofsB);
        #pragma unroll
        for (int tt = 0; tt < 4; ++tt) {
            short8 afr = *reinterpret_cast<const short8*>(
                A_lds + (tt * 16 + cl) * 1024 + (((s * 64) ^ aoff) + hi * 16));
            acc[tt][0] = __builtin_amdgcn_mfma_f32_16x16x32_bf16(afr, bfr0, acc[tt][0], 0, 0, 0);
            acc[tt][1] = __builtin_amdgcn_mfma_f32_16x16x32_bf16(afr, bfr1, acc[tt][1], 0, 0, 0);
        }
    }

    __syncthreads();   // all waves done with A_lds -> safe to alias scorebuf
    float* scorebuf = (float*)A_lds;   // [16][64]

    // ---- epilogue: inv (L2 re-read), tanh, w2-dot, per-wave partials ----
    #pragma unroll
    for (int tt = 0; tt < 4; ++tt) {
        float4 iv = *reinterpret_cast<const float4*>(inv_norm + row0 + tt * 16 + hi * 4);
        float sp[4] = {0.f, 0.f, 0.f, 0.f};
        #pragma unroll
        for (int f = 0; f < 2; ++f) {
            int col = w * 32 + f * 16 + cl;
            float wv = W2v[col];
            float bb = b1[col];
            sp[0] += wv * fast_tanh(acc[tt][f][0] * iv.x + bb);
            sp[1] += wv * fast_tanh(acc[tt][f][1] * iv.y + bb);
            sp[2] += wv * fast_tanh(acc[tt][f][2] * iv.z + bb);
            sp[3] += wv * fast_tanh(acc[tt][f][3] * iv.w + bb);
        }
        #pragma unroll
        for (int i = 0; i < 4; ++i) {
            float v = sp[i];
            v += __shfl_xor(v, 1, 64);
            v += __shfl_xor(v, 2, 64);
            v += __shfl_xor(v, 4, 64);
            v += __shfl_xor(v, 8, 64);
            if (cl == 0) scorebuf[w * 64 + tt * 16 + hi * 4 + i] = v;
        }
    }
    __syncthreads();

    // sum the 16 per-wave col-slice partials -> final scores
    if (t < 64) {
        float sres = 0.f;
        #pragma unroll
        for (int q = 0; q < 16; ++q) sres += scorebuf[q * 64 + t];
        scores[row0 + t] = sres;
    }
}

// ---- kernel 3: softmax over r + fp32 weighted pooling (R16 verbatim) ----
__global__ __launch_bounds__(512) void softmax_pool(
    const float* __restrict__ x, const float* __restrict__ inv_norm,
    const float* __restrict__ scores, float* __restrict__ out) {

    __shared__ float F[RREG];
    __shared__ float wts[RREG];
    const int t = threadIdx.x;
    const int g = blockIdx.x;

    float s = 0.f, e = 0.f;
    if (t < RREG) { s = scores[g * RREG + t]; F[t] = s; }
    __syncthreads();
    for (int off = 128; off > 0; off >>= 1) {
        if (t < off) F[t] = fmaxf(F[t], F[t + off]);
        __syncthreads();
    }
    float mx = F[0];
    __syncthreads();
    if (t < RREG) { e = expf(s - mx); F[t] = e; }
    __syncthreads();
    for (int off = 128; off > 0; off >>= 1) {
        if (t < off) F[t] += F[t + off];
        __syncthreads();
    }
    float denom = F[0];
    if (t < RREG) {
        float al = e / denom;
        out[FBAR_ELEMS + (size_t)g * RREG + t] = al;          // output 1: alphas
        wts[t] = al * inv_norm[(size_t)g * RREG + t];
    }
    __syncthreads();

    // fbar[d=t] = sum_r (alpha_r * inv_r) * x[g,r,t]  (coalesced 2 KB/row)
    float a = 0.f;
    const float* xb = x + (size_t)g * RREG * D + t;
    #pragma unroll 16
    for (int r = 0; r < RREG; ++r) a += wts[r] * xb[(size_t)r * D];
    out[(size_t)g * D + t] = a;                               // output 0: fbar
}

extern "C" void kernel_launch(void* const* d_in, const int* in_sizes, int n_in,
                              void* d_out, int out_size, void* d_ws, size_t ws_size,
                              hipStream_t stream) {
    const float* x  = (const float*)d_in[0];
    const float* W1 = (const float*)d_in[1];
    const float* b1 = (const float*)d_in[2];
    const float* w2 = (const float*)d_in[3];
    // b2 (d_in[4]) shifts all scores uniformly -> softmax-invariant -> unused.
    float* out = (float*)d_out;

    unsigned short* W1c = (unsigned short*)d_ws;                     // 512 KiB
    float* inv_norm = (float*)((char*)d_ws + 524288);                // 512 KiB
    float* scores   = (float*)((char*)d_ws + 1048576);               // 512 KiB

    conv_w1<<<256, 256, 0, stream>>>(W1, W1c);
    score_gemm<<<ROWS / 64, 1024, 0, stream>>>(x, W1c, b1, w2, inv_norm, scores);
    softmax_pool<<<NGROUP, 512, 0, stream>>>(x, inv_norm, scores, out);
}

// Round 20
// 152.955 us; speedup vs baseline: 1.2229x; 1.2229x over previous
//
#include <hip/hip_runtime.h>
#include <hip/hip_bf16.h>

typedef short short8 __attribute__((ext_vector_type(8)));
typedef float floatx4 __attribute__((ext_vector_type(4)));

#define NGROUP 512
#define RREG 256
#define D 512
#define ROWS 131072
#define FBAR_ELEMS (NGROUP * D)   // 262144

__device__ __forceinline__ unsigned short f2bf(float f) {
    unsigned int u = __float_as_uint(f);
    unsigned int r = (u + 0x7fffu + ((u >> 16) & 1u)) >> 16;
    return (unsigned short)r;
}
__device__ __forceinline__ float fast_tanh(float x) {
    float cx = fminf(fmaxf(x, -9.5f), 9.5f);
    float e  = __builtin_amdgcn_exp2f(cx * 2.8853900817779268f);  // e^{2cx}
    return (e - 1.f) * __builtin_amdgcn_rcpf(e + 1.f);
}

// ---- kernel 1: W1 fp32 -> bf16, K-CHUNKED PRE-SWIZZLED layout (R16 verbatim) ----
// W1c = 16 chunks of 32 KiB. Chunk kc holds k in [kc*32,kc*32+32) for all 512
// cols: element (col, kc*32+kl) at chunk byte col*64 + ((kl*2) ^ (((col>>1)&3)<<4)).
__global__ __launch_bounds__(256) void conv_w1(const float* __restrict__ W1,
                                               unsigned short* __restrict__ W1c) {
    int tid = blockIdx.x * 256 + threadIdx.x;   // 0..65535
    int P = tid * 8;                            // byte offset in 512 KiB image
    int kc = P >> 15;
    int L = P & 32767;
    int col = L >> 6;
    int q = L & 63;
    int kl = (q ^ (((col >> 1) & 3) << 4)) >> 1;   // multiple of 4
    const float* src = W1 + col * 512 + kc * 32 + kl;
    float4 v = *reinterpret_cast<const float4*>(src);
    ushort4 o;
    o.x = f2bf(v.x); o.y = f2bf(v.y); o.z = f2bf(v.z); o.w = f2bf(v.w);
    *reinterpret_cast<ushort4*>((char*)W1c + P) = o;
}

// ---- kernel 2: score GEMM = R16 (160us winner) minus the vmcnt(0) drain ----
// 2048 blocks x 512 threads (8 waves), block = 64 rows x full N=512,
// __launch_bounds__(512,4) -> VGPR cap 64, acc[4][4] in AGPR half, 43% occ,
// 2 blocks/CU (LDS 78 KB). Identical swizzles/epilogue to R16.
// SYNC: raw {lgkmcnt(0); s_barrier} orders the A-pack handoff only; B
// readiness via counted vmcnt(5) (wave-private slices: own 4 DMA ops + 1
// newer x-load outstanding); x prefetched at distance 2 - never drained.
// R19 BUGFIX (tail): B(15) must go to buf 1 (matched with A(15) in buf 1;
// buf 1's B last read at s=13, fenced). R19 staged it into buf 0, racing
// with compute(0)'s B(14) reads AND leaving s=15 to read stale B(13).
__global__ __launch_bounds__(512, 4) void score_gemm(
    const float* __restrict__ x, const unsigned short* __restrict__ W1c,
    const float* __restrict__ b1, const float* __restrict__ W2v,
    float* __restrict__ inv_norm, float* __restrict__ scores) {

    __shared__ unsigned short A_lds[2][64 * 32];    // 2 x 4 KB
    __shared__ unsigned short B_lds[2][512 * 32];   // 2 x 32 KB
    __shared__ float ss_lds[64][8];                 // 2 KB
    __shared__ float inv_s[64];
    __shared__ float scorebuf[8][64];               // 2 KB

    const int t = threadIdx.x;
    const int lane = t & 63;
    const int w = t >> 6;          // wave 0..7
    const int cl = lane & 15;
    const int hi = lane >> 4;
    const size_t row0 = (size_t)blockIdx.x * 64;

    // B stage: wave w DMAs its OWN 64-col slice (4 KB = 4 ops) of chunk kc;
    // wave w also reads exactly cols w*64..w*64+64 -> own-wave vmcnt suffices.
    auto stageB = [&](int buf, int kc) {
        const char* gb = (const char*)W1c + kc * 32768 + w * 4096 + lane * 16;
        char* lb = (char*)B_lds[buf] + w * 4096;
        #pragma unroll
        for (int i = 0; i < 4; ++i) {
            __builtin_amdgcn_global_load_lds(
                (const __attribute__((address_space(1))) void*)(gb + i * 1024),
                (__attribute__((address_space(3))) void*)(lb + i * 1024),
                16, 0, 0);
        }
    };

    // A staging: thread t owns row t>>3, k-quad t&7 of each 64x32 chunk.
    const int arow = t >> 3;
    const int abyte = arow * 64 + (((t & 7) * 8) ^ (((arow >> 1) & 3) << 4));
    const float* xbase = x + (row0 + arow) * (size_t)D + (t & 7) * 4;

    float ssacc = 0.f;
    auto packA = [&](int buf, const float4& xv) {
        ssacc += xv.x * xv.x + xv.y * xv.y + xv.z * xv.z + xv.w * xv.w;
        ushort4 pk;
        pk.x = f2bf(xv.x); pk.y = f2bf(xv.y); pk.z = f2bf(xv.z); pk.w = f2bf(xv.w);
        *reinterpret_cast<ushort4*>((char*)A_lds[buf] + abyte) = pk;
    };

    // ---- prologue: B(0) staged; x(0), x(1) in flight; A(0) packed ----
    stageB(0, 0);
    float4 xr0 = *reinterpret_cast<const float4*>(xbase);        // x(0)
    float4 xr1 = *reinterpret_cast<const float4*>(xbase + 32);   // x(1)
    packA(0, xr0);
    __syncthreads();   // one-time full drain: A(0) visible, B(0) landed

    floatx4 acc[4][4];
    #pragma unroll
    for (int tt = 0; tt < 4; ++tt)
        #pragma unroll
        for (int f = 0; f < 4; ++f) acc[tt][f] = floatx4{0, 0, 0, 0};

    const int fofs = (hi * 16) ^ (((cl >> 1) & 3) << 4);   // shared A/B frag swizzle

    auto compute = [&](int cur) {
        short8 afr[4], bfr[4];
        #pragma unroll
        for (int tt = 0; tt < 4; ++tt)
            afr[tt] = *reinterpret_cast<const short8*>(
                (char*)A_lds[cur] + (tt * 16 + cl) * 64 + fofs);
        #pragma unroll
        for (int f = 0; f < 4; ++f)
            bfr[f] = *reinterpret_cast<const short8*>(
                (char*)B_lds[cur] + (w * 64 + f * 16 + cl) * 64 + fofs);
        #pragma unroll
        for (int tt = 0; tt < 4; ++tt)
            #pragma unroll
            for (int f = 0; f < 4; ++f)
                acc[tt][f] = __builtin_amdgcn_mfma_f32_16x16x32_bf16(
                    afr[tt], bfr[f], acc[tt][f], 0, 0, 0);
    };

    // ---- main loop s = 0..13 ----
    // Invariant at vmcnt(5): outstanding = {x(s+2), B(s+1)x4} -> B(s) landed.
    // B-buf nx was last read at s-1 (all reads fenced by that step's
    // lgkmcnt(0)+s_barrier); A-buf nx writes likewise barrier-ordered.
    #pragma unroll 2
    for (int s = 0; s < 14; ++s) {
        const int cur = s & 1, nx = cur ^ 1;
        float4 xn = *reinterpret_cast<const float4*>(xbase + (s + 2) * 32);  // x(s+2)
        stageB(nx, s + 1);                       // B(s+1) -> freed buffer
        asm volatile("s_waitcnt vmcnt(5)" ::: "memory");   // B(s) landed
        compute(cur);
        packA(nx, (s & 1) ? xr0 : xr1);          // pack x(s+1)
        if (s & 1) xr1 = xn; else xr0 = xn;      // retire slot with x(s+2)
        asm volatile("s_waitcnt lgkmcnt(0)\ns_barrier" ::: "memory");
    }
    // ---- s = 14 (cur = 0) ----
    {
        stageB(1, 15);                           // B(15) -> buf 1 (R19 fix: NOT buf 0;
                                                 // buf1 B last read s=13, fenced)
        asm volatile("s_waitcnt vmcnt(4)" ::: "memory");   // B(14) landed (B(15)x4 newer)
        compute(0);                              // A(14),B(14) from buf 0
        packA(1, xr1);                           // pack x(15) -> A buf 1
        asm volatile("s_waitcnt lgkmcnt(0)\ns_barrier" ::: "memory");
    }
    // ---- s = 15 (cur = 1) ----
    {
        asm volatile("s_waitcnt vmcnt(0)" ::: "memory");   // B(15) landed
        compute(1);                              // A(15),B(15) from buf 1
    }

    // ---- inv from accumulated ss ----
    ss_lds[arow][t & 7] = ssacc;
    __syncthreads();
    if (t < 64) {
        float ss = 0.f;
        #pragma unroll
        for (int j = 0; j < 8; ++j) ss += ss_lds[t][j];
        float inv = 1.0f / fmaxf(sqrtf(ss), 1e-12f);
        inv_s[t] = inv;
        inv_norm[row0 + t] = inv;
    }
    __syncthreads();

    // ---- epilogue: inv, tanh, w2-dot -> per-row partials (R16 verbatim) ----
    float sp[4][4];
    #pragma unroll
    for (int tt = 0; tt < 4; ++tt)
        #pragma unroll
        for (int i = 0; i < 4; ++i) sp[tt][i] = 0.f;

    #pragma unroll
    for (int f = 0; f < 4; ++f) {
        int col = w * 64 + f * 16 + cl;
        float wv = W2v[col];
        float bb = b1[col];
        #pragma unroll
        for (int tt = 0; tt < 4; ++tt) {
            #pragma unroll
            for (int i = 0; i < 4; ++i) {
                float iv = inv_s[tt * 16 + hi * 4 + i];
                sp[tt][i] += wv * fast_tanh(acc[tt][f][i] * iv + bb);
            }
        }
    }

    #pragma unroll
    for (int tt = 0; tt < 4; ++tt) {
        #pragma unroll
        for (int i = 0; i < 4; ++i) {
            float v = sp[tt][i];
            v += __shfl_xor(v, 1, 64);
            v += __shfl_xor(v, 2, 64);
            v += __shfl_xor(v, 4, 64);
            v += __shfl_xor(v, 8, 64);
            if (cl == 0) scorebuf[w][tt * 16 + hi * 4 + i] = v;
        }
    }
    __syncthreads();

    if (t < 64) {
        float s = 0.f;
        #pragma unroll
        for (int q = 0; q < 8; ++q) s += scorebuf[q][t];
        scores[row0 + t] = s;
    }
}

// ---- kernel 3: softmax over r + fp32 weighted pooling (R16 verbatim) ----
__global__ __launch_bounds__(512) void softmax_pool(
    const float* __restrict__ x, const float* __restrict__ inv_norm,
    const float* __restrict__ scores, float* __restrict__ out) {

    __shared__ float F[RREG];
    __shared__ float wts[RREG];
    const int t = threadIdx.x;
    const int g = blockIdx.x;

    float s = 0.f, e = 0.f;
    if (t < RREG) { s = scores[g * RREG + t]; F[t] = s; }
    __syncthreads();
    for (int off = 128; off > 0; off >>= 1) {
        if (t < off) F[t] = fmaxf(F[t], F[t + off]);
        __syncthreads();
    }
    float mx = F[0];
    __syncthreads();
    if (t < RREG) { e = expf(s - mx); F[t] = e; }
    __syncthreads();
    for (int off = 128; off > 0; off >>= 1) {
        if (t < off) F[t] += F[t + off];
        __syncthreads();
    }
    float denom = F[0];
    if (t < RREG) {
        float al = e / denom;
        out[FBAR_ELEMS + (size_t)g * RREG + t] = al;          // output 1: alphas
        wts[t] = al * inv_norm[(size_t)g * RREG + t];
    }
    __syncthreads();

    // fbar[d=t] = sum_r (alpha_r * inv_r) * x[g,r,t]  (coalesced 2 KB/row)
    float a = 0.f;
    const float* xb = x + (size_t)g * RREG * D + t;
    #pragma unroll 16
    for (int r = 0; r < RREG; ++r) a += wts[r] * xb[(size_t)r * D];
    out[(size_t)g * D + t] = a;                               // output 0: fbar
}

extern "C" void kernel_launch(void* const* d_in, const int* in_sizes, int n_in,
                              void* d_out, int out_size, void* d_ws, size_t ws_size,
                              hipStream_t stream) {
    const float* x  = (const float*)d_in[0];
    const float* W1 = (const float*)d_in[1];
    const float* b1 = (const float*)d_in[2];
    const float* w2 = (const float*)d_in[3];
    // b2 (d_in[4]) shifts all scores uniformly -> softmax-invariant -> unused.
    float* out = (float*)d_out;

    unsigned short* W1c = (unsigned short*)d_ws;                     // 512 KiB
    float* inv_norm = (float*)((char*)d_ws + 524288);                // 512 KiB
    float* scores   = (float*)((char*)d_ws + 1048576);               // 512 KiB

    conv_w1<<<256, 256, 0, stream>>>(W1, W1c);
    score_gemm<<<ROWS / 64, 512, 0, stream>>>(x, W1c, b1, w2, inv_norm, scores);
    softmax_pool<<<NGROUP, 512, 0, stream>>>(x, inv_norm, scores, out);
}